// Round 16
// baseline (4160.447 us; speedup 1.0000x reference)
//
#include <hip/hip_runtime.h>

#define TMAX 8192
#define H 128

typedef int   i32x4 __attribute__((ext_vector_type(4)));

__device__ __forceinline__ float sigf(float x) {
    return __builtin_amdgcn_rcpf(1.f + __expf(-x));
}
__device__ __forceinline__ float tanhf_fast(float x) {
    return fmaf(2.f, __builtin_amdgcn_rcpf(1.f + __expf(-2.f * x)), -1.f);
}

// One block, 256 threads = 4 waves, ONE wave per SIMD.
//
// ROUND 16: R15's wall = matrix(255) + VALU(580) serial, where VALU = 2
// barrier-locked waves/SIMD x ~290 cyc of IDENTICAL epilogue (per-wave
// epilogue cost is constant — R13/R14 evidence). Halve the VALU term by
// running 1 wave/SIMD: each wave owns 8 tiles (16 MFMA, 8 indep depth-2
// chains; matrix work per SIMD unchanged), epilogue redundancy 4->2 way,
// tile-select 1-of-8 (m&7). Numerics BIT-IDENTICAL to R15 (same int8
// quantization, chunk order, epilogue) -> absmax must repeat 9.77e-4.
__attribute__((amdgpu_waves_per_eu(1, 1)))
__global__ __launch_bounds__(256)
void lstm_seq_kernel(const float* __restrict__ x,
                     const float* __restrict__ Wih,
                     const float* __restrict__ Whh,
                     const float* __restrict__ bih,
                     const float* __restrict__ bhh,
                     const float* __restrict__ Wlin,
                     const float* __restrict__ blin,
                     const float* __restrict__ h0,
                     const float* __restrict__ c0,
                     float* __restrict__ out,
                     int T)
{
    __shared__ float  x_s[TMAX];    // 32 KB
    __shared__ float  srow[512];    // per-row |W|max (2 KB)
    __shared__ i32x4  hv4[2][8];    // double-buffered h as 128 int8

    const int t   = threadIdx.x;    // 0..255
    const int l   = t & 63;
    const int w   = t >> 6;         // wave 0..3
    const int m   = l & 15;         // A row-within-tile / C col (replicated)
    const int g16 = l >> 4;         // C row-group

    for (int idx = t; idx < T; idx += 256) x_s[idx] = x[idx];

    // ---- per-row absmax of Whh (2 rows per thread, one-time) ----
    for (int r = t; r < 512; r += 256) {
        const float* row = Whh + r * H;
        float mx = 0.f;
        for (int k = 0; k < H; ++k) mx = fmaxf(mx, fabsf(row[k]));
        srow[r] = fmaxf(mx, 1e-30f);
    }
    __syncthreads();

    // ---- pack A fragments: int8, per-row scale 127/rowmax (as R15) ----
    // Tile tau (0..7): within-tile row m -> gate m&3, jj m>>2;
    // R = (m&3)*H + w*32 + tau*4 + (m>>2). Elem i of chunk c:
    // K = c*64 + g16*16 + i, byte i of dword i>>2... (R15-verified k-map).
    i32x4 Aq[8][2];
    #pragma unroll
    for (int tau = 0; tau < 8; ++tau) {
        const int R = (m & 3) * H + w * 32 + tau * 4 + (m >> 2);
        const float inv = 127.f / srow[R];
        const float* rp = Whh + R * H;
        #pragma unroll
        for (int c = 0; c < 2; ++c) {
            int wd0 = 0, wd1 = 0, wd2 = 0, wd3 = 0;
            #pragma unroll
            for (int i = 0; i < 4; ++i) {
                const int base = c * 64 + g16 * 16;
                wd0 |= (((int)rintf(rp[base +  0 + i] * inv)) & 0xFF) << (i * 8);
                wd1 |= (((int)rintf(rp[base +  4 + i] * inv)) & 0xFF) << (i * 8);
                wd2 |= (((int)rintf(rp[base +  8 + i] * inv)) & 0xFF) << (i * 8);
                wd3 |= (((int)rintf(rp[base + 12 + i] * inv)) & 0xFF) << (i * 8);
            }
            Aq[tau][c] = (i32x4){wd0, wd1, wd2, wd3};
        }
    }

    // ---- epilogue constants ----
    const int msel  = m & 7;             // tile select (2-way redundant in m>>3)
    const int jproc = w * 32 + msel * 4 + g16;
    const float sc0 = srow[0 * H + jproc] * (1.f / 16129.f);
    const float sc1 = srow[1 * H + jproc] * (1.f / 16129.f);
    const float sc2 = srow[2 * H + jproc] * (1.f / 16129.f);
    const float sc3 = srow[3 * H + jproc] * (1.f / 16129.f);
    const float wx0 = Wih[0 * H + jproc];
    const float wx1 = Wih[1 * H + jproc];
    const float wx2 = Wih[2 * H + jproc];
    const float wx3 = Wih[3 * H + jproc];
    const float b0  = bih[0 * H + jproc] + bhh[0 * H + jproc];
    const float b1  = bih[1 * H + jproc] + bhh[1 * H + jproc];
    const float b2  = bih[2 * H + jproc] + bhh[2 * H + jproc];
    const float b3  = bih[3 * H + jproc] + bhh[3 * H + jproc];
    float c = c0[jproc];                 // 2-way redundant (bit-identical math)
    const bool writer = (m < 8);         // one writer per (tile, g16)

    const i32x4 zeroC = {0, 0, 0, 0};

    if (t < H) {
        ((signed char*)hv4[0])[t] = (signed char)(int)rintf(h0[t] * 127.f);
    }
    __syncthreads();

#define MFMA(A, B, C) __builtin_amdgcn_mfma_i32_16x16x64_i8((A), (B), (C), 0, 0, 0)
#define SEL(K) ((msel & 4) ? ((msel & 2) ? ((msel & 1) ? a7[K] : a6[K]) \
                                         : ((msel & 1) ? a5[K] : a4[K])) \
                           : ((msel & 2) ? ((msel & 1) ? a3[K] : a2[K]) \
                                         : ((msel & 1) ? a1[K] : a0[K])))

#define STEP(RD, WR, SIDX) { \
    const float xv = x_s[SIDX]; \
    const i32x4 B0 = hv4[RD][g16]; \
    const i32x4 B1 = hv4[RD][4 + g16]; \
    i32x4 a0 = MFMA(Aq[0][0], B0, zeroC); \
    i32x4 a1 = MFMA(Aq[1][0], B0, zeroC); \
    i32x4 a2 = MFMA(Aq[2][0], B0, zeroC); \
    i32x4 a3 = MFMA(Aq[3][0], B0, zeroC); \
    i32x4 a4 = MFMA(Aq[4][0], B0, zeroC); \
    i32x4 a5 = MFMA(Aq[5][0], B0, zeroC); \
    i32x4 a6 = MFMA(Aq[6][0], B0, zeroC); \
    i32x4 a7 = MFMA(Aq[7][0], B0, zeroC); \
    a0 = MFMA(Aq[0][1], B1, a0); \
    a1 = MFMA(Aq[1][1], B1, a1); \
    a2 = MFMA(Aq[2][1], B1, a2); \
    a3 = MFMA(Aq[3][1], B1, a3); \
    a4 = MFMA(Aq[4][1], B1, a4); \
    a5 = MFMA(Aq[5][1], B1, a5); \
    a6 = MFMA(Aq[6][1], B1, a6); \
    a7 = MFMA(Aq[7][1], B1, a7); \
    const float gi = fmaf((float)SEL(0), sc0, fmaf(xv, wx0, b0)); \
    const float gf = fmaf((float)SEL(1), sc1, fmaf(xv, wx1, b1)); \
    const float gg = fmaf((float)SEL(2), sc2, fmaf(xv, wx2, b2)); \
    const float go = fmaf((float)SEL(3), sc3, fmaf(xv, wx3, b3)); \
    const float ig = sigf(gi); \
    const float fg = sigf(gf); \
    const float g2 = tanhf_fast(gg); \
    const float og = sigf(go); \
    c = fmaf(fg, c, ig * g2); \
    const float hn = og * tanhf_fast(c); \
    if (writer) ((signed char*)hv4[WR])[jproc] = (signed char)(int)rintf(hn * 127.f); \
    __syncthreads(); }

    const int Teven = T & ~1;
    for (int s = 0; s < Teven; s += 2) {
        STEP(0, 1, s)
        STEP(1, 0, s + 1)
    }
    if (T & 1) { STEP(0, 1, T - 1) }
    const signed char* hf = (const signed char*)hv4[T & 1];
#undef STEP
#undef SEL
#undef MFMA

    // Final linear: out = dot(W_lin, h_T) + b_lin (wave 0).
    if (t < 64) {
        const float h0f = (float)hf[t]      * (1.f / 127.f);
        const float h1f = (float)hf[t + 64] * (1.f / 127.f);
        float v = Wlin[t] * h0f + Wlin[t + 64] * h1f;
        #pragma unroll
        for (int off = 32; off >= 1; off >>= 1) v += __shfl_down(v, off);
        if (t == 0) out[0] = v + blin[0];
    }
}

extern "C" void kernel_launch(void* const* d_in, const int* in_sizes, int n_in,
                              void* d_out, int out_size, void* d_ws, size_t ws_size,
                              hipStream_t stream) {
    const float* x    = (const float*)d_in[0];
    const float* Wih  = (const float*)d_in[1];
    const float* Whh  = (const float*)d_in[2];
    const float* bih  = (const float*)d_in[3];
    const float* bhh  = (const float*)d_in[4];
    const float* Wlin = (const float*)d_in[5];
    const float* blin = (const float*)d_in[6];
    const float* h0   = (const float*)d_in[7];
    const float* c0   = (const float*)d_in[8];
    float* out = (float*)d_out;
    const int T = in_sizes[0];

    lstm_seq_kernel<<<1, 256, 0, stream>>>(x, Wih, Whh, bih, bhh, Wlin, blin,
                                           h0, c0, out, T);
}

// Round 18
// 3290.739 us; speedup vs baseline: 1.2643x; 1.2643x over previous
//
#include <hip/hip_runtime.h>

#define TMAX 8192
#define H 128

typedef int   i32x4 __attribute__((ext_vector_type(4)));

__device__ __forceinline__ float rcpf_(float x) { return __builtin_amdgcn_rcpf(x); }
// full tanh for the c-path (same ops as R15's tanhf_fast)
__device__ __forceinline__ float tanhf_fast(float x) {
    return fmaf(2.f, rcpf_(1.f + __expf(-2.f * x)), -1.f);
}
// quad broadcast via DPP quad_perm — pattern must be a compile-time constant
// (R17 lesson: update_dpp rejects runtime args even from literal call sites).
template <int PAT>
__device__ __forceinline__ float qbcast(float v) {
    return __int_as_float(__builtin_amdgcn_update_dpp(0, __float_as_int(v),
                                                      PAT, 0xF, 0xF, true));
}

// One block, 512 threads = 8 waves (2/SIMD) — R15 geometry (the proven best).
//
// ROUND 18 = R17 with the DPP pattern as a template parameter:
// R16 proved R15 is ISSUE-bound at 2 waves/SIMD (835 issue vs 888 wall) and
// that dropping to 1 wave just exposes latency. So cut per-wave VALU issue:
// GATE-PER-LANE epilogue. Lane (m,g16) = (tile m>>2, gate m&3, j-group g16)
// — 64 lanes = 4x4x4 = zero redundancy (R15 was 4-way redundant: each lane
// ran all 4 gate activations = 10 quarter-rate transcendentals). Now 1
// activation/lane via the shared sigmoid core (px,cA,cB) = (-1,1,0) for
// sigmoids, (-2,2,-1) for tanh — operation-identical to R15's
// sigf/tanhf_fast, so absmax must repeat 9.77e-4 exactly. 4 DPP
// quad-broadcasts distribute (i,f,g,o); everyone updates c.
// MFMA section: unchanged from R15 (int8, per-row scale, K-chunked).
__attribute__((amdgpu_waves_per_eu(2, 2)))
__global__ __launch_bounds__(512)
void lstm_seq_kernel(const float* __restrict__ x,
                     const float* __restrict__ Wih,
                     const float* __restrict__ Whh,
                     const float* __restrict__ bih,
                     const float* __restrict__ bhh,
                     const float* __restrict__ Wlin,
                     const float* __restrict__ blin,
                     const float* __restrict__ h0,
                     const float* __restrict__ c0,
                     float* __restrict__ out,
                     int T)
{
    __shared__ float  x_s[TMAX];    // 32 KB
    __shared__ float  srow[512];    // per-row |W|max (2 KB)
    __shared__ i32x4  hv4[2][8];    // double-buffered h as 128 int8

    const int t   = threadIdx.x;    // 0..511
    const int l   = t & 63;
    const int w   = t >> 6;         // wave 0..7
    const int m   = l & 15;         // A row-within-tile / C col
    const int g16 = l >> 4;         // C row-group

    for (int idx = t; idx < T; idx += 512) x_s[idx] = x[idx];

    // ---- per-row absmax of Whh (one row per thread, one-time) ----
    {
        const float* row = Whh + t * H;
        float mx = 0.f;
        for (int k = 0; k < H; ++k) mx = fmaxf(mx, fabsf(row[k]));
        srow[t] = fmaxf(mx, 1e-30f);
    }
    __syncthreads();

    // ---- pack A fragments: int8, per-row scale 127/rowmax (R15-verified) ----
    i32x4 Aq[4][2];
    #pragma unroll
    for (int tau = 0; tau < 4; ++tau) {
        const int R = (m & 3) * H + w * 16 + tau * 4 + (m >> 2);
        const float inv = 127.f / srow[R];
        const float* rp = Whh + R * H;
        #pragma unroll
        for (int c = 0; c < 2; ++c) {
            int wd0 = 0, wd1 = 0, wd2 = 0, wd3 = 0;
            #pragma unroll
            for (int i = 0; i < 4; ++i) {
                const int base = c * 64 + g16 * 16;
                wd0 |= (((int)rintf(rp[base +  0 + i] * inv)) & 0xFF) << (i * 8);
                wd1 |= (((int)rintf(rp[base +  4 + i] * inv)) & 0xFF) << (i * 8);
                wd2 |= (((int)rintf(rp[base +  8 + i] * inv)) & 0xFF) << (i * 8);
                wd3 |= (((int)rintf(rp[base + 12 + i] * inv)) & 0xFF) << (i * 8);
            }
            Aq[tau][c] = (i32x4){wd0, wd1, wd2, wd3};
        }
    }

    // ---- gate-per-lane epilogue constants ----
    const int tsel  = (m >> 2) & 3;      // tile  -> j
    const int gsel  = m & 3;             // gate  (0=i,1=f,2=g,3=o)
    const int jproc = w * 16 + tsel * 4 + g16;
    const int Rg    = gsel * H + jproc;  // this lane's W-row
    const float scg = srow[Rg] * (1.f / 16129.f);
    const float wxg = Wih[Rg];
    const float bg  = bih[Rg] + bhh[Rg];
    const float px  = (gsel == 2) ? -2.f : -1.f;  // exp prescale
    const float cA  = (gsel == 2) ?  2.f :  1.f;  // post fma: cA*r + cB
    const float cB  = (gsel == 2) ? -1.f :  0.f;
    float c = c0[jproc];                 // replicated across the quad
    const bool writer = (gsel == 0);     // one writer per (tile, g16)

    const i32x4 zeroC = {0, 0, 0, 0};

    if (t < H) {
        ((signed char*)hv4[0])[t] = (signed char)(int)rintf(h0[t] * 127.f);
    }
    __syncthreads();

#define MFMA(A, B, C) __builtin_amdgcn_mfma_i32_16x16x64_i8((A), (B), (C), 0, 0, 0)
    // 16-way select: acc-flat[m] = a_{m>>2}[m&3] (masks are loop-invariant)
#define SEL16() \
    ((m & 8) ? ((m & 4) ? ((m & 2) ? ((m & 1) ? a3[3] : a3[2]) \
                                   : ((m & 1) ? a3[1] : a3[0])) \
                        : ((m & 2) ? ((m & 1) ? a2[3] : a2[2]) \
                                   : ((m & 1) ? a2[1] : a2[0]))) \
             : ((m & 4) ? ((m & 2) ? ((m & 1) ? a1[3] : a1[2]) \
                                   : ((m & 1) ? a1[1] : a1[0])) \
                        : ((m & 2) ? ((m & 1) ? a0[3] : a0[2]) \
                                   : ((m & 1) ? a0[1] : a0[0]))))

#define STEP(RD, WR, SIDX) { \
    const float xv = x_s[SIDX]; \
    const i32x4 B0 = hv4[RD][g16]; \
    const i32x4 B1 = hv4[RD][4 + g16]; \
    i32x4 a0 = MFMA(Aq[0][0], B0, zeroC); \
    i32x4 a1 = MFMA(Aq[1][0], B0, zeroC); \
    i32x4 a2 = MFMA(Aq[2][0], B0, zeroC); \
    i32x4 a3 = MFMA(Aq[3][0], B0, zeroC); \
    a0 = MFMA(Aq[0][1], B1, a0); \
    a1 = MFMA(Aq[1][1], B1, a1); \
    a2 = MFMA(Aq[2][1], B1, a2); \
    a3 = MFMA(Aq[3][1], B1, a3); \
    const float gate = fmaf((float)SEL16(), scg, fmaf(xv, wxg, bg)); \
    const float e    = __expf(px * gate); \
    const float act  = fmaf(cA, rcpf_(1.f + e), cB); \
    const float ig = qbcast<0x00>(act); \
    const float fg = qbcast<0x55>(act); \
    const float g2 = qbcast<0xAA>(act); \
    const float og = qbcast<0xFF>(act); \
    c = fmaf(fg, c, ig * g2); \
    const float hn = og * tanhf_fast(c); \
    if (writer) ((signed char*)hv4[WR])[jproc] = (signed char)(int)rintf(hn * 127.f); \
    __syncthreads(); }

    const int Teven = T & ~1;
    for (int s = 0; s < Teven; s += 2) {
        STEP(0, 1, s)
        STEP(1, 0, s + 1)
    }
    if (T & 1) { STEP(0, 1, T - 1) }
    const signed char* hf = (const signed char*)hv4[T & 1];
#undef STEP
#undef SEL16
#undef MFMA

    // Final linear: out = dot(W_lin, h_T) + b_lin (wave 0).
    if (t < 64) {
        const float h0f = (float)hf[t]      * (1.f / 127.f);
        const float h1f = (float)hf[t + 64] * (1.f / 127.f);
        float v = Wlin[t] * h0f + Wlin[t + 64] * h1f;
        #pragma unroll
        for (int off = 32; off >= 1; off >>= 1) v += __shfl_down(v, off);
        if (t == 0) out[0] = v + blin[0];
    }
}

extern "C" void kernel_launch(void* const* d_in, const int* in_sizes, int n_in,
                              void* d_out, int out_size, void* d_ws, size_t ws_size,
                              hipStream_t stream) {
    const float* x    = (const float*)d_in[0];
    const float* Wih  = (const float*)d_in[1];
    const float* Whh  = (const float*)d_in[2];
    const float* bih  = (const float*)d_in[3];
    const float* bhh  = (const float*)d_in[4];
    const float* Wlin = (const float*)d_in[5];
    const float* blin = (const float*)d_in[6];
    const float* h0   = (const float*)d_in[7];
    const float* c0   = (const float*)d_in[8];
    float* out = (float*)d_out;
    const int T = in_sizes[0];

    lstm_seq_kernel<<<1, 512, 0, stream>>>(x, Wih, Whh, bih, bhh, Wlin, blin,
                                           h0, c0, out, T);
}

// Round 19
// 2842.606 us; speedup vs baseline: 1.4636x; 1.1576x over previous
//
#include <hip/hip_runtime.h>

#define TMAX 8192
#define H 128

typedef int   i32x4 __attribute__((ext_vector_type(4)));

__device__ __forceinline__ float sigf(float x) {
    return __builtin_amdgcn_rcpf(1.f + __expf(-x));
}
__device__ __forceinline__ float tanhf_fast(float x) {
    return fmaf(2.f, __builtin_amdgcn_rcpf(1.f + __expf(-2.f * x)), -1.f);
}

// One block, 512 threads = 8 waves (2/SIMD) — R15 structure (proven 3033 us,
// issue-bound at 835 issue-cyc vs 888 wall).
//
// ROUND 19: kill the AGPR-read tax on the epilogue. VGPR_Count=88 proves the
// RA parks MFMA accumulators in AGPRs; the SEL cndmask tree + cvts then pay
// ~16 v_accvgpr_read per lane per step (the unexplained ~70 inst/wave).
// Fix via asm MFMA with explicit register classes:
//   - A-fragment  "a"  : long-lived weights stay in AGPRs (MFMA reads native)
//   - B, C        "v"  : fresh-from-LDS / chain values
//   - D           "=&v": accumulators BORN in arch VGPRs -> epilogue reads free
// (Inverse of R9's failure: there "v" was forced on LONG-lived values causing
// per-use copies; here the "v" values are intra-step temporaries.)
// Math/layout/epilogue byte-identical to R15 -> absmax must repeat 9.77e-4.
__attribute__((amdgpu_waves_per_eu(2, 2)))
__global__ __launch_bounds__(512)
void lstm_seq_kernel(const float* __restrict__ x,
                     const float* __restrict__ Wih,
                     const float* __restrict__ Whh,
                     const float* __restrict__ bih,
                     const float* __restrict__ bhh,
                     const float* __restrict__ Wlin,
                     const float* __restrict__ blin,
                     const float* __restrict__ h0,
                     const float* __restrict__ c0,
                     float* __restrict__ out,
                     int T)
{
    __shared__ float  x_s[TMAX];    // 32 KB
    __shared__ float  srow[512];    // per-row |W|max (2 KB)
    __shared__ i32x4  hv4[2][8];    // double-buffered h as 128 int8

    const int t   = threadIdx.x;    // 0..511
    const int l   = t & 63;
    const int w   = t >> 6;         // wave 0..7
    const int m   = l & 15;         // A row-within-tile / C col
    const int g16 = l >> 4;         // C row-group

    for (int idx = t; idx < T; idx += 512) x_s[idx] = x[idx];

    // ---- per-row absmax of Whh (one row per thread, one-time) ----
    {
        const float* row = Whh + t * H;
        float mx = 0.f;
        for (int k = 0; k < H; ++k) mx = fmaxf(mx, fabsf(row[k]));
        srow[t] = fmaxf(mx, 1e-30f);
    }
    __syncthreads();

    // ---- pack A fragments: int8, per-row scale 127/rowmax (R15-verified) ----
    i32x4 Aq[4][2];
    #pragma unroll
    for (int tau = 0; tau < 4; ++tau) {
        const int R = (m & 3) * H + w * 16 + tau * 4 + (m >> 2);
        const float inv = 127.f / srow[R];
        const float* rp = Whh + R * H;
        #pragma unroll
        for (int c = 0; c < 2; ++c) {
            int wd0 = 0, wd1 = 0, wd2 = 0, wd3 = 0;
            #pragma unroll
            for (int i = 0; i < 4; ++i) {
                const int base = c * 64 + g16 * 16;
                wd0 |= (((int)rintf(rp[base +  0 + i] * inv)) & 0xFF) << (i * 8);
                wd1 |= (((int)rintf(rp[base +  4 + i] * inv)) & 0xFF) << (i * 8);
                wd2 |= (((int)rintf(rp[base +  8 + i] * inv)) & 0xFF) << (i * 8);
                wd3 |= (((int)rintf(rp[base + 12 + i] * inv)) & 0xFF) << (i * 8);
            }
            Aq[tau][c] = (i32x4){wd0, wd1, wd2, wd3};
        }
    }

    // ---- epilogue constants (identical to R15) ----
    const int tsel  = (l >> 2) & 3;
    const int jproc = w * 16 + tsel * 4 + g16;
    const float sc0 = srow[0 * H + jproc] * (1.f / 16129.f);
    const float sc1 = srow[1 * H + jproc] * (1.f / 16129.f);
    const float sc2 = srow[2 * H + jproc] * (1.f / 16129.f);
    const float sc3 = srow[3 * H + jproc] * (1.f / 16129.f);
    const float wx0 = Wih[0 * H + jproc];
    const float wx1 = Wih[1 * H + jproc];
    const float wx2 = Wih[2 * H + jproc];
    const float wx3 = Wih[3 * H + jproc];
    const float b0  = bih[0 * H + jproc] + bhh[0 * H + jproc];
    const float b1  = bih[1 * H + jproc] + bhh[1 * H + jproc];
    const float b2  = bih[2 * H + jproc] + bhh[2 * H + jproc];
    const float b3  = bih[3 * H + jproc] + bhh[3 * H + jproc];
    float c = c0[jproc];                 // 4-way redundant (bit-identical math)
    const bool writer = ((l & 3) == 0);  // one col per (tile,jj) writes h

    if (t < H) {
        ((signed char*)hv4[0])[t] = (signed char)(int)rintf(h0[t] * 127.f);
    }
    __syncthreads();

    // asm MFMA: A from AGPR ("a"), B/C VGPR, D forced to fresh arch VGPRs.
#define MFMA_AV(D, A, B, C) \
    asm("v_mfma_i32_16x16x64_i8 %0, %1, %2, %3" \
        : "=&v"(D) : "a"(A), "v"(B), "v"(C));

#define SEL(K) ((tsel & 2) ? ((tsel & 1) ? a3[K] : a2[K]) \
                           : ((tsel & 1) ? a1[K] : a0[K]))

#define STEP(RD, WR, SIDX) { \
    const float xv = x_s[SIDX]; \
    const i32x4 B0 = hv4[RD][g16]; \
    const i32x4 B1 = hv4[RD][4 + g16]; \
    const i32x4 zc = {0, 0, 0, 0}; \
    i32x4 p0, p1, p2, p3, a0, a1, a2, a3; \
    MFMA_AV(p0, Aq[0][0], B0, zc) \
    MFMA_AV(p1, Aq[1][0], B0, zc) \
    MFMA_AV(p2, Aq[2][0], B0, zc) \
    MFMA_AV(p3, Aq[3][0], B0, zc) \
    MFMA_AV(a0, Aq[0][1], B1, p0) \
    MFMA_AV(a1, Aq[1][1], B1, p1) \
    MFMA_AV(a2, Aq[2][1], B1, p2) \
    MFMA_AV(a3, Aq[3][1], B1, p3) \
    const float gi = fmaf((float)SEL(0), sc0, fmaf(xv, wx0, b0)); \
    const float gf = fmaf((float)SEL(1), sc1, fmaf(xv, wx1, b1)); \
    const float gg = fmaf((float)SEL(2), sc2, fmaf(xv, wx2, b2)); \
    const float go = fmaf((float)SEL(3), sc3, fmaf(xv, wx3, b3)); \
    const float ig = sigf(gi); \
    const float fg = sigf(gf); \
    const float g2 = tanhf_fast(gg); \
    const float og = sigf(go); \
    c = fmaf(fg, c, ig * g2); \
    const float hn = og * tanhf_fast(c); \
    if (writer) ((signed char*)hv4[WR])[jproc] = (signed char)(int)rintf(hn * 127.f); \
    __syncthreads(); }

    const int Teven = T & ~1;
    for (int s = 0; s < Teven; s += 2) {
        STEP(0, 1, s)
        STEP(1, 0, s + 1)
    }
    if (T & 1) { STEP(0, 1, T - 1) }
    const signed char* hf = (const signed char*)hv4[T & 1];
#undef STEP
#undef SEL
#undef MFMA_AV

    // Final linear: out = dot(W_lin, h_T) + b_lin (wave 0).
    if (t < 64) {
        const float h0f = (float)hf[t]      * (1.f / 127.f);
        const float h1f = (float)hf[t + 64] * (1.f / 127.f);
        float v = Wlin[t] * h0f + Wlin[t + 64] * h1f;
        #pragma unroll
        for (int off = 32; off >= 1; off >>= 1) v += __shfl_down(v, off);
        if (t == 0) out[0] = v + blin[0];
    }
}

extern "C" void kernel_launch(void* const* d_in, const int* in_sizes, int n_in,
                              void* d_out, int out_size, void* d_ws, size_t ws_size,
                              hipStream_t stream) {
    const float* x    = (const float*)d_in[0];
    const float* Wih  = (const float*)d_in[1];
    const float* Whh  = (const float*)d_in[2];
    const float* bih  = (const float*)d_in[3];
    const float* bhh  = (const float*)d_in[4];
    const float* Wlin = (const float*)d_in[5];
    const float* blin = (const float*)d_in[6];
    const float* h0   = (const float*)d_in[7];
    const float* c0   = (const float*)d_in[8];
    float* out = (float*)d_out;
    const int T = in_sizes[0];

    lstm_seq_kernel<<<1, 512, 0, stream>>>(x, Wih, Whh, bih, bhh, Wlin, blin,
                                           h0, c0, out, T);
}